// Round 9
// baseline (257.253 us; speedup 1.0000x reference)
//
#include <hip/hip_runtime.h>
#include <hip/hip_bf16.h>
#include <stdint.h>

#define IMG_H 96
#define IMG_W 96
#define IMG_C 3
#define HO    90                 // 96-7+1
#define NPAT  8100               // 90*90
#define NPAD  8192
#define DDIM  147                // 3*7*7
#define KPAD  160                // padded K (5 chunks of 32)
#define NCHK  5
#define BATCH 4
#define TILE  128
#define NT    (NPAD / TILE)      // 64 stream tiles
#define ALPHA 0.05f
// embedded-scalar columns (inside zero-pad K range 147..159):
//   Yp: cols 148-149 = y2 (bf16 hi/lo pair), 150-151 = rms pair (by prep_rms)
//   Xp: cols 152-153 = x2 pair
// Disjoint -> every cross term has one true-zero operand -> GEMM unchanged.
#define EBY 148
#define EBX 152

typedef __attribute__((ext_vector_type(8))) short short8;
typedef __attribute__((ext_vector_type(4))) float f32x4;

__device__ __forceinline__ void async16(const void* g, void* l) {
    __builtin_amdgcn_global_load_lds(
        (const __attribute__((address_space(1))) unsigned int*)g,
        (__attribute__((address_space(3))) unsigned int*)l,
        16, 0, 0);
}

// split float into two bf16 (hi+lo), both finite; decode = exact to ~2^-16 rel
__device__ __forceinline__ unsigned enc_pair(float v) {
    unsigned hb = __float_as_uint(v) >> 16;
    float lo = v - __uint_as_float(hb << 16);
    unsigned lb = __float_as_uint(lo) >> 16;
    return hb | (lb << 16);
}
__device__ __forceinline__ float dec_pair(unsigned u) {
    return __uint_as_float(u << 16) + __uint_as_float(u & 0xFFFF0000u);
}

// ---------- patch extraction + squared norms (+ embed pair, + out zero) ----------
__global__ __launch_bounds__(256) void extract_patches(
    const float* __restrict__ img,          // [B][3][96][96]
    __hip_bfloat16* __restrict__ pat,       // [B][NPAD][KPAD]
    float* __restrict__ nrm,                // [B][NPAD]
    int eb,                                 // embed base col
    float* __restrict__ outzero)            // may be null
{
    int wid  = threadIdx.x >> 6;
    int lane = threadIdx.x & 63;
    int pidx = blockIdx.x * 4 + wid;        // 0..8191
    int b    = blockIdx.y;
    if (pidx >= NPAD) return;
    if (outzero && blockIdx.x == 0 && blockIdx.y == 0 && threadIdx.x == 0)
        outzero[0] = 0.f;
    const float* im = img + (size_t)b * (IMG_C * IMG_H * IMG_W);
    __hip_bfloat16* pp = pat + ((size_t)b * NPAD + pidx) * KPAD;
    int r = pidx / HO, c = pidx - r * HO;
    bool valid = pidx < NPAT;
    float ss = 0.f;
    for (int d = lane; d < KPAD; d += 64) {
        float v = 0.f;
        if (valid && d < DDIM) {
            int ch  = d / 49;
            int rem = d - ch * 49;
            int pr  = rem / 7, pc = rem - pr * 7;
            v = im[ch * (IMG_H * IMG_W) + (r + pr) * IMG_W + (c + pc)];
        }
        if (d < eb || d >= eb + 2) pp[d] = __float2bfloat16(v); // lane0 owns embed
        ss += v * v;
    }
    for (int s = 32; s; s >>= 1) ss += __shfl_down(ss, s);
    if (lane == 0) {
        nrm[(size_t)b * NPAD + pidx] = ss;
        *(unsigned*)&pp[eb] = enc_pair(ss);
    }
}

// ---------- rms prep: write invD/(rm+a) pair into Yp cols 150-151 ----------
__global__ __launch_bounds__(256) void prep_rms(
    const float* __restrict__ row_min, __hip_bfloat16* __restrict__ Yp)
{
    int i = blockIdx.x * 256 + threadIdx.x;
    if (i < BATCH * NPAD) {
        int j = i & (NPAD - 1);
        float v = (j < NPAT) ? (1.0f / (float)DDIM) / (row_min[i] + ALPHA)
                             : 1e30f;   // finite pad mask (never wins min)
        *(unsigned*)&Yp[(size_t)i * KPAD + 150] = enc_pair(v);
    }
}

// -------------------- panel-persistent fused GEMM passes --------------------
// R8 skeleton + T4 counted vmcnt: 3 stream buffers, depth-2 prefetch,
// one raw s_barrier/tile, vmcnt(5) (never 0 until last tile). All per-tile
// scalars ride inside the staged tile (embedded pad-col pairs) so the loop
// has EXACTLY 5 VMEM ops/thread/tile and the count is exact.
template <int PASS>
__global__ __launch_bounds__(512, 2) void panel_pass(
    const __hip_bfloat16* __restrict__ Xp,   // [B][NPAD][KPAD]
    const __hip_bfloat16* __restrict__ Yp,   // [B][NPAD][KPAD]
    const float* __restrict__ y2,            // PASS1 final store only
    float* __restrict__ row_min,
    float* __restrict__ out)                 // PASS2 only
{
    __shared__ __align__(16) __hip_bfloat16 S[3][NCHK * TILE * 32]; // 3 x 40 KB
    __shared__ float red[4][TILE];

    int blk = blockIdx.x;
    int bz  = blk & 3;               // image (XCD-constant under %8 rr)
    int tP  = blk >> 2;              // panel index 0..63
    int tid = threadIdx.x;
    int wid = tid >> 6, lane = tid & 63;
    int wp  = wid >> 2;              // panel group (2 x 64 rows)
    int ws  = wid & 3;               // stream group (4 x 32 cols)

    const __hip_bfloat16* Pbase =
        (PASS == 1 ? Yp : Xp) + ((size_t)bz * NPAD + tP * TILE) * KPAD;
    const __hip_bfloat16* Sbase =
        (PASS == 1 ? Xp : Yp) + (size_t)bz * NPAD * KPAD;

    // stage one 128x160 tile: 5 async16/thread (inverse-swizzled source)
    auto stageS = [&](int buf, const __hip_bfloat16* gsrc) {
        int row  = wid * 16 + (lane >> 2);
        int slog = (lane & 3) ^ ((row >> 1) & 3);
        const __hip_bfloat16* src = gsrc + (size_t)row * KPAD + slog * 8;
        __hip_bfloat16* dbase = &S[buf][wid * 512];
        for (int c = 0; c < NCHK; ++c)
            async16(src + c * 32, dbase + c * 4096);
    };

    // prologue: panel -> S2, tiles 0,1 -> S0,S1
    stageS(2, Pbase);
    stageS(0, Sbase);
    stageS(1, Sbase + (size_t)TILE * KPAD);
    asm volatile("s_waitcnt vmcnt(10)" ::: "memory");   // panel landed
    __builtin_amdgcn_s_barrier();
    __builtin_amdgcn_sched_barrier(0);

    int fr    = lane & 15;
    int sread = ((lane >> 4) ^ ((lane >> 1) & 3)) * 8;  // swizzled 16B slot
    int prow  = wp * 64 + fr;
    int srow  = ws * 32 + fr;

    short8 p_reg[NCHK][4];
#pragma unroll
    for (int c = 0; c < NCHK; ++c)
#pragma unroll
        for (int m = 0; m < 4; ++m)
            p_reg[c][m] =
                *(const short8*)&S[2][c * 4096 + (prow + m * 16) * 32 + sread];

    float xv[4];   // PASS2: panel cols' x2 from embedded pair (Xp 152-153)
    if (PASS == 2)
#pragma unroll
        for (int nb = 0; nb < 4; ++nb) {
            int pr = wp * 64 + nb * 16 + fr;
            unsigned u = *(const unsigned*)
                &S[2][4 * 4096 + pr * 32 + (3 ^ ((pr >> 1) & 3)) * 8];
            xv[nb] = dec_pair(u);
        }

    // p_reg/xv must be IN REGISTERS before S2 is overwritten at t=0 (rule 18)
    asm volatile("s_waitcnt lgkmcnt(0)" ::: "memory");
    __builtin_amdgcn_sched_barrier(0);

    float runmin[PASS == 1 ? 16 : 4];
#pragma unroll
    for (int i = 0; i < (PASS == 1 ? 16 : 4); ++i)
        runmin[i] = __builtin_inff();

#pragma unroll 1
    for (int t = 0; t < NT; ++t) {
        // counted wait: tile t landed; tile t+1's 5 loads stay in flight
        if (t == NT - 1) asm volatile("s_waitcnt vmcnt(0)" ::: "memory");
        else             asm volatile("s_waitcnt vmcnt(5)" ::: "memory");
        __builtin_amdgcn_s_barrier();
        __builtin_amdgcn_sched_barrier(0);
        if (t + 2 < NT)                      // depth-2 prefetch
            stageS((t + 2) % 3, Sbase + (size_t)(t + 2) * TILE * KPAD);

        const __hip_bfloat16* Sc = &S[t % 3][0];

        if (PASS == 1) {
            f32x4 acc[4][2] = {};
            __builtin_amdgcn_s_setprio(1);
#pragma unroll
            for (int c = 0; c < NCHK; ++c) {
                short8 s0 = *(const short8*)&Sc[c * 4096 + srow * 32 + sread];
                short8 s1 = *(const short8*)&Sc[c * 4096 + (srow + 16) * 32 + sread];
#pragma unroll
                for (int m = 0; m < 4; ++m) {
                    acc[m][0] = __builtin_amdgcn_mfma_f32_16x16x32_bf16(
                        p_reg[c][m], s0, acc[m][0], 0, 0, 0);
                    acc[m][1] = __builtin_amdgcn_mfma_f32_16x16x32_bf16(
                        p_reg[c][m], s1, acc[m][1], 0, 0, 0);
                }
            }
            __builtin_amdgcn_s_setprio(0);
            int gcb = t * TILE;
            float xvn[2];
#pragma unroll
            for (int n = 0; n < 2; ++n) {
                int ic = ws * 32 + n * 16 + fr;
                unsigned u = *(const unsigned*)
                    &Sc[4 * 4096 + ic * 32 + (3 ^ ((ic >> 1) & 3)) * 8];
                xvn[n] = (gcb + ic < NPAT) ? dec_pair(u) : __builtin_inff();
            }
#pragma unroll
            for (int m = 0; m < 4; ++m)
#pragma unroll
                for (int reg = 0; reg < 4; ++reg)
#pragma unroll
                    for (int n = 0; n < 2; ++n)
                        runmin[m * 4 + reg] = fminf(runmin[m * 4 + reg],
                            fmaf(-2.0f, acc[m][n][reg], xvn[n]));
        } else {
            f32x4 acc[2][4] = {};
            __builtin_amdgcn_s_setprio(1);
#pragma unroll
            for (int c = 0; c < NCHK; ++c) {
                short8 s0 = *(const short8*)&Sc[c * 4096 + srow * 32 + sread];
                short8 s1 = *(const short8*)&Sc[c * 4096 + (srow + 16) * 32 + sread];
#pragma unroll
                for (int nb = 0; nb < 4; ++nb) {
                    acc[0][nb] = __builtin_amdgcn_mfma_f32_16x16x32_bf16(
                        s0, p_reg[c][nb], acc[0][nb], 0, 0, 0);
                    acc[1][nb] = __builtin_amdgcn_mfma_f32_16x16x32_bf16(
                        s1, p_reg[c][nb], acc[1][nb], 0, 0, 0);
                }
            }
            __builtin_amdgcn_s_setprio(0);
#pragma unroll
            for (int ma = 0; ma < 2; ++ma)
#pragma unroll
                for (int reg = 0; reg < 4; ++reg) {
                    int jl = ws * 32 + ma * 16 + (lane >> 4) * 4 + reg;
                    const unsigned* pq = (const unsigned*)
                        &Sc[4 * 4096 + jl * 32 + (2 ^ ((jl >> 1) & 3)) * 8 + 4];
                    float yv = dec_pair(pq[0]);
                    float rr = dec_pair(pq[1]);   // 1e30 on pad rows
#pragma unroll
                    for (int nb = 0; nb < 4; ++nb)
                        runmin[nb] = fminf(runmin[nb],
                            fmaf(-2.0f, acc[ma][nb][reg], yv + xv[nb]) * rr);
                }
        }
    }

    if (PASS == 1) {
#pragma unroll
        for (int m = 0; m < 4; ++m)
#pragma unroll
            for (int reg = 0; reg < 4; ++reg) {
                float v = runmin[m * 4 + reg];
                for (int s = 1; s < 16; s <<= 1)
                    v = fminf(v, __shfl_xor(v, s));
                if ((lane & 15) == 0)
                    red[ws][wp * 64 + m * 16 + (lane >> 4) * 4 + reg] = v;
            }
        __syncthreads();
        if (tid < TILE) {
            float mv = fminf(fminf(red[0][tid], red[1][tid]),
                             fminf(red[2][tid], red[3][tid]));
            float y2g = y2[(size_t)bz * NPAD + tP * TILE + tid];
            row_min[(size_t)bz * NPAD + tP * TILE + tid] =
                fmaxf(y2g + mv, 0.f) * (1.0f / (float)DDIM);
        }
    } else {
#pragma unroll
        for (int nb = 0; nb < 4; ++nb) {
            float v = runmin[nb];
            v = fminf(v, __shfl_xor(v, 16));
            v = fminf(v, __shfl_xor(v, 32));
            if (lane < 16) red[ws][wp * 64 + nb * 16 + lane] = v;
        }
        __syncthreads();
        if (tid < TILE) {
            int gc = tP * TILE + tid;
            float cv = fminf(fminf(red[0][tid], red[1][tid]),
                             fminf(red[2][tid], red[3][tid]));
            cv = fmaxf(cv, 0.f);                   // deferred clamp (monotone)
            red[0][tid] = (gc < NPAT) ? cv : 0.f;  // mask pad cols
        }
        __syncthreads();
        if (tid < 64) {
            float s = red[0][tid] + red[0][tid + 64];
            for (int o = 32; o; o >>= 1) s += __shfl_down(s, o);
            if (tid == 0)
                atomicAdd(out, s * (1.0f / (float)(BATCH * NPAT)));
        }
    }
}

extern "C" void kernel_launch(void* const* d_in, const int* in_sizes, int n_in,
                              void* d_out, int out_size, void* d_ws, size_t ws_size,
                              hipStream_t stream) {
    const float* x = (const float*)d_in[0];
    const float* y = (const float*)d_in[1];
    float* out = (float*)d_out;

    char* ws = (char*)d_ws;
    size_t patSz = (size_t)BATCH * NPAD * KPAD * sizeof(__hip_bfloat16); // 10.5 MB
    __hip_bfloat16* Xp = (__hip_bfloat16*)ws;
    __hip_bfloat16* Yp = (__hip_bfloat16*)(ws + patSz);
    float* x2 = (float*)(ws + 2 * patSz);
    float* y2 = x2 + BATCH * NPAD;
    float* row_min = y2 + BATCH * NPAD;

    dim3 eg(NPAD / 4, BATCH);
    extract_patches<<<eg, 256, 0, stream>>>(x, Xp, x2, EBX, out); // zeroes out
    extract_patches<<<eg, 256, 0, stream>>>(y, Yp, y2, EBY, nullptr);

    panel_pass<1><<<NT * BATCH, 512, 0, stream>>>(Xp, Yp, y2, row_min, out);
    prep_rms<<<(BATCH * NPAD) / 256, 256, 0, stream>>>(row_min, Yp);
    panel_pass<2><<<NT * BATCH, 512, 0, stream>>>(Xp, Yp, y2, row_min, out);
}